// Round 1
// baseline (603.285 us; speedup 1.0000x reference)
//
#include <hip/hip_runtime.h>

#define NT    8192
#define NOUT  515          // 2*nlag + 3
#define PAD   257          // nlag + 1
#define TC    2048         // t-chunk staged in LDS
#define XSPAN (TC + 511)   // x window span per chunk: t in [0,TC) + lag0+i in [0,512)

// Main kernel: lags 0..511 (lag index l, actual lag = l - 257).
// One block per channel. 256 threads = 4 waves.
// Lane owns 8 contiguous lags; waves split the t-range of each chunk 4-ways.
__global__ __launch_bounds__(256) void xcorr_main(const float* __restrict__ x,
                                                  const float* __restrict__ y,
                                                  float* __restrict__ out) {
    __shared__ __align__(16) float xs[XSPAN];
    __shared__ __align__(16) float ys[TC];   // reused as reduction buffer at the end

    const int c    = blockIdx.x;
    const int tid  = threadIdx.x;
    const int lane = tid & 63;
    const int wave = tid >> 6;
    const int lag0 = lane * 8;               // lag block [lag0, lag0+8)

    const float* xg = x + (size_t)c * NT;
    const float* yg = y + (size_t)c * NT;

    float acc[8];
#pragma unroll
    for (int i = 0; i < 8; ++i) acc[i] = 0.f;

    for (int t0 = 0; t0 < NT; t0 += TC) {
        // ---- stage chunk into LDS (coalesced, zero-padded x edges) ----
        for (int i = tid; i < XSPAN; i += 256) {
            int gx = t0 + i - PAD;
            xs[i] = (gx >= 0 && gx < NT) ? xg[gx] : 0.f;
        }
        for (int i = tid; i < TC; i += 256) {
            ys[i] = yg[t0 + i];
        }
        __syncthreads();

        // ---- compute: wave handles t in [tbeg, tend) of this chunk ----
        const int tbeg = wave * (TC / 4);
        const int tend = tbeg + (TC / 4);

        float w[16];
        {
            const float4 a = *(const float4*)&xs[tbeg + lag0];
            const float4 b = *(const float4*)&xs[tbeg + lag0 + 4];
            w[0]=a.x; w[1]=a.y; w[2]=a.z; w[3]=a.w;
            w[4]=b.x; w[5]=b.y; w[6]=b.z; w[7]=b.w;
        }
        for (int t = tbeg; t < tend; t += 8) {
            const float4 xa = *(const float4*)&xs[t + lag0 + 8];
            const float4 xb = *(const float4*)&xs[t + lag0 + 12];
            w[8]=xa.x;  w[9]=xa.y;  w[10]=xa.z; w[11]=xa.w;
            w[12]=xb.x; w[13]=xb.y; w[14]=xb.z; w[15]=xb.w;
            const float4 ya = *(const float4*)&ys[t];
            const float4 yb = *(const float4*)&ys[t + 4];
            const float yv[8] = {ya.x, ya.y, ya.z, ya.w, yb.x, yb.y, yb.z, yb.w};
#pragma unroll
            for (int s = 0; s < 8; ++s) {
#pragma unroll
                for (int i = 0; i < 8; ++i)
                    acc[i] = fmaf(w[s + i], yv[s], acc[i]);
            }
#pragma unroll
            for (int j = 0; j < 8; ++j) w[j] = w[j + 8];
        }
        __syncthreads();   // before next chunk overwrites LDS
    }

    // ---- cross-wave reduction (reuse ys as 4x512 buffer) ----
    float* red = ys;
#pragma unroll
    for (int i = 0; i < 8; ++i) red[wave * 512 + lag0 + i] = acc[i];
    __syncthreads();
    for (int l = tid; l < 512; l += 256) {
        float s = red[l] + red[512 + l] + red[1024 + l] + red[1536 + l];
        out[(size_t)c * NOUT + l] = s;
    }
}

// Tail kernel: lags 512..514 (actual lag 255..257) — 3 dot products per channel.
__global__ __launch_bounds__(256) void xcorr_tail(const float* __restrict__ x,
                                                  const float* __restrict__ y,
                                                  float* __restrict__ out) {
    __shared__ float sred[3][256];
    const int c   = blockIdx.x;
    const int tid = threadIdx.x;
    const float* xg = x + (size_t)c * NT;
    const float* yg = y + (size_t)c * NT;

    float a0 = 0.f, a1 = 0.f, a2 = 0.f;
    for (int t = tid; t < NT; t += 256) {
        float yv = yg[t];
        int i0 = t + 255;
        if (i0     < NT) a0 = fmaf(xg[i0],     yv, a0);
        if (i0 + 1 < NT) a1 = fmaf(xg[i0 + 1], yv, a1);
        if (i0 + 2 < NT) a2 = fmaf(xg[i0 + 2], yv, a2);
    }
    sred[0][tid] = a0; sred[1][tid] = a1; sred[2][tid] = a2;
    __syncthreads();
    for (int s = 128; s > 0; s >>= 1) {
        if (tid < s) {
            sred[0][tid] += sred[0][tid + s];
            sred[1][tid] += sred[1][tid + s];
            sred[2][tid] += sred[2][tid + s];
        }
        __syncthreads();
    }
    if (tid < 3) out[(size_t)c * NOUT + 512 + tid] = sred[tid][0];
}

extern "C" void kernel_launch(void* const* d_in, const int* in_sizes, int n_in,
                              void* d_out, int out_size, void* d_ws, size_t ws_size,
                              hipStream_t stream) {
    const float* d1 = (const float*)d_in[0];   // data1 (x)
    const float* d2 = (const float*)d_in[1];   // data2 (y)
    float* out = (float*)d_out;
    const int nch = in_sizes[0] / NT;          // 32*64 = 2048 channels

    xcorr_main<<<dim3(nch), dim3(256), 0, stream>>>(d1, d2, out);
    xcorr_tail<<<dim3(nch), dim3(256), 0, stream>>>(d1, d2, out);
}

// Round 2
// 443.992 us; speedup vs baseline: 1.3588x; 1.3588x over previous
//
#include <hip/hip_runtime.h>

#define NT    8192
#define NOUT  515          // 2*nlag + 3
#define PAD   257          // nlag + 1
#define TC    2048         // t-chunk staged in LDS
#define NW    4            // waves per block
#define TW    (TC / NW)    // 512 t-steps per wave
#define XDW   2592         // xs dwords: >= TC+514 needed (2562); 648 chunks (mult of 8)

// 16B-chunk XOR swizzle: bijective within each aligned 8-chunk block,
// spreads stride-2-chunk wave reads evenly over all 8 bank groups.
#define SWZC(c) ((c) ^ (((c) >> 3) & 7))
#define XIDX(i) ((SWZC((i) >> 2) << 2) | ((i) & 3))   // swizzled dword index

// One block per channel, 4 waves. Lane owns 8 contiguous lags (lag0 = 8*lane);
// waves split each chunk's t-range 4-ways. Lags 512..514 fused (tail accs).
__global__ __launch_bounds__(256) void xcorr_fused(const float* __restrict__ x,
                                                   const float* __restrict__ y,
                                                   float* __restrict__ out) {
    __shared__ __align__(16) float xs[XDW];
    __shared__ __align__(16) float ys[TC];
    __shared__ float redT[NW][3];

    const int c    = blockIdx.x;
    const int tid  = threadIdx.x;
    const int lane = tid & 63;
    const int wave = tid >> 6;
    const int lag0 = lane << 3;

    const float* xg = x + (size_t)c * NT;
    const float* yg = y + (size_t)c * NT;
    float* og = out + (size_t)c * NOUT;

    float acc[8] = {0.f, 0.f, 0.f, 0.f, 0.f, 0.f, 0.f, 0.f};
    float t0a = 0.f, t1a = 0.f, t2a = 0.f;   // tail lags 512,513,514

    const float4* xs4 = (const float4*)xs;

    for (int t0 = 0; t0 < NT; t0 += TC) {
        // ---- stage (swizzled xs, linear ys) ----
        for (int i = tid; i < XDW; i += 256) {
            int gx = t0 + i - PAD;
            xs[XIDX(i)] = (gx >= 0 && gx < NT) ? xg[gx] : 0.f;
        }
        for (int i = tid; i < TC; i += 256) ys[i] = yg[t0 + i];
        __syncthreads();

        const int tbeg = wave * TW;

        // ---- main lags: sliding 16-reg window, two-phase (no shift movs) ----
        float w[16];
        {
            int cb = (tbeg >> 2) + (lane << 1);     // chunk of (tbeg + lag0)
            float4 A = xs4[SWZC(cb)];
            float4 B = xs4[SWZC(cb + 1)];
            w[0]=A.x; w[1]=A.y; w[2]=A.z; w[3]=A.w;
            w[4]=B.x; w[5]=B.y; w[6]=B.z; w[7]=B.w;
        }
        for (int t = tbeg; t < tbeg + TW; t += 16) {
            { // phase A: consume w[0..7] as old, load w[8..15] for t+8
                int cc = ((t + 8) >> 2) + (lane << 1);
                float4 xa = xs4[SWZC(cc)];
                float4 xb = xs4[SWZC(cc + 1)];
                w[8]=xa.x;  w[9]=xa.y;  w[10]=xa.z; w[11]=xa.w;
                w[12]=xb.x; w[13]=xb.y; w[14]=xb.z; w[15]=xb.w;
                float4 ya = *(const float4*)&ys[t];
                float4 yb = *(const float4*)&ys[t + 4];
                const float yv[8] = {ya.x, ya.y, ya.z, ya.w, yb.x, yb.y, yb.z, yb.w};
#pragma unroll
                for (int s = 0; s < 8; ++s)
#pragma unroll
                    for (int i = 0; i < 8; ++i)
                        acc[i] = fmaf(w[s + i], yv[s], acc[i]);
            }
            { // phase B: consume w[8..15] as old, load w[0..7] for t+16
                int cc = ((t + 16) >> 2) + (lane << 1);
                float4 xa = xs4[SWZC(cc)];
                float4 xb = xs4[SWZC(cc + 1)];
                w[0]=xa.x; w[1]=xa.y; w[2]=xa.z; w[3]=xa.w;
                w[4]=xb.x; w[5]=xb.y; w[6]=xb.z; w[7]=xb.w;
                float4 ya = *(const float4*)&ys[t + 8];
                float4 yb = *(const float4*)&ys[t + 12];
                const float yv[8] = {ya.x, ya.y, ya.z, ya.w, yb.x, yb.y, yb.z, yb.w};
#pragma unroll
                for (int s = 0; s < 8; ++s)
#pragma unroll
                    for (int i = 0; i < 8; ++i)
                        acc[i] = fmaf(w[((8 + s + i) & 15)], yv[s], acc[i]);
            }
        }

        // ---- tail lags 512..514: consecutive-lane reads (conflict-free) ----
#pragma unroll
        for (int b = 0; b < 8; ++b) {
            int tt = tbeg + (b << 6) + lane;
            float yv = ys[tt];
            int xi = tt + 512;
            t0a = fmaf(xs[XIDX(xi)],     yv, t0a);
            t1a = fmaf(xs[XIDX(xi + 1)], yv, t1a);
            t2a = fmaf(xs[XIDX(xi + 2)], yv, t2a);
        }
        __syncthreads();   // before next chunk overwrites LDS
    }

    // ---- cross-wave reduction for main lags (reuse ys) ----
    float4* red4 = (float4*)ys;
    red4[wave * 128 + (lane << 1)]     = make_float4(acc[0], acc[1], acc[2], acc[3]);
    red4[wave * 128 + (lane << 1) + 1] = make_float4(acc[4], acc[5], acc[6], acc[7]);

    // ---- tail: butterfly within wave, then cross-wave via redT ----
#pragma unroll
    for (int m = 32; m >= 1; m >>= 1) {
        t0a += __shfl_xor(t0a, m);
        t1a += __shfl_xor(t1a, m);
        t2a += __shfl_xor(t2a, m);
    }
    if (lane == 0) { redT[wave][0] = t0a; redT[wave][1] = t1a; redT[wave][2] = t2a; }
    __syncthreads();

    const float* red = ys;
    for (int l = tid; l < 512; l += 256)
        og[l] = red[l] + red[512 + l] + red[1024 + l] + red[1536 + l];
    if (tid < 3)
        og[512 + tid] = redT[0][tid] + redT[1][tid] + redT[2][tid] + redT[3][tid];
}

extern "C" void kernel_launch(void* const* d_in, const int* in_sizes, int n_in,
                              void* d_out, int out_size, void* d_ws, size_t ws_size,
                              hipStream_t stream) {
    const float* d1 = (const float*)d_in[0];   // data1 (x)
    const float* d2 = (const float*)d_in[1];   // data2 (y)
    float* out = (float*)d_out;
    const int nch = in_sizes[0] / NT;          // 32*64 = 2048 channels

    xcorr_fused<<<dim3(nch), dim3(256), 0, stream>>>(d1, d2, out);
}

// Round 3
// 288.795 us; speedup vs baseline: 2.0890x; 1.5374x over previous
//
#include <hip/hip_runtime.h>

typedef __attribute__((ext_vector_type(4))) float  f32x4;
typedef __attribute__((ext_vector_type(8))) short  bfx8;
typedef __attribute__((ext_vector_type(4))) short  bfx4;

#define NT    8192
#define NOUT  515
#define PAD   257
#define TCH   2048
#define XGRAN 328                 // 16B granules (8 bf16) in x region -> 2624 elems
#define XBYTES (XGRAN * 16)       // 5248
#define YGRAN 536                 // 8B granules (4 bf16) per y replica -> 2144 slots
#define YBASE XBYTES
#define YBYTES (2184 * 8)         // replica granule bases {3,552,1100,1648}, end 2184
#define LDSZ  (XBYTES + YBYTES + 64)

// x granule swizzle: XOR low-3 granule bits with block id (stays in 8-block, bijective)
__device__ __forceinline__ int swz(int G) { return G ^ ((G >> 3) & 7); }

__device__ __forceinline__ unsigned short f2bf(float v) {
    unsigned int u = __float_as_uint(v);
    return (unsigned short)((u + 0x7FFFu + ((u >> 16) & 1u)) >> 16);
}
__device__ __forceinline__ float bf2f(unsigned short u) {
    return __uint_as_float(((unsigned int)u) << 16);
}

__global__ __launch_bounds__(256) void xcorr_mfma(const float* __restrict__ x,
                                                  const float* __restrict__ y,
                                                  float* __restrict__ out) {
    __shared__ __align__(16) char lds[LDSZ];

    const int c    = blockIdx.x;
    const int tid  = threadIdx.x;
    const int lane = tid & 63;
    const int wv   = tid >> 6;
    const int g    = lane >> 4;       // k-group
    const int r    = lane & 15;       // A row (m low) == B col (q)
    const int s    = (4 - (r & 3)) & 3;                 // y replica id for this col
    const int gb   = (s == 0) ? 3 : (s == 1) ? 552 : (s == 2) ? 1100 : 1648;

    const float* xg = x + (size_t)c * NT;
    const float* yg = y + (size_t)c * NT;
    float* og = out + (size_t)c * NOUT;

    f32x4 acc0 = {0.f, 0.f, 0.f, 0.f};   // m-tile 0 (m 0..15)
    f32x4 acc1 = {0.f, 0.f, 0.f, 0.f};   // m-tile 1 (m 16..31)
    float ta0 = 0.f, ta1 = 0.f, ta2 = 0.f;  // tail lags 512..514

    for (int chunk = 0; chunk < 4; ++chunk) {
        const int t0g = chunk * TCH;

        // ---- stage x window: elem e -> xg[t0g + e - 257], bf16, swizzled granules ----
        for (int G = tid; G < XGRAN; G += 256) {
            const int e0 = G * 8;
            unsigned int pk[4];
#pragma unroll
            for (int h = 0; h < 4; ++h) {
                int i0 = t0g + e0 + 2 * h - PAD;
                int i1 = i0 + 1;
                float a = (i0 >= 0 && i0 < NT) ? xg[i0] : 0.f;
                float b = (i1 >= 0 && i1 < NT) ? xg[i1] : 0.f;
                pk[h] = (unsigned int)f2bf(a) | ((unsigned int)f2bf(b) << 16);
            }
            *(uint4*)(lds + (swz(G) << 4)) = make_uint4(pk[0], pk[1], pk[2], pk[3]);
        }
        // ---- stage y replicas: replica S slot w -> yg[t0g + w - 32 + S] ----
#pragma unroll
        for (int S = 0; S < 4; ++S) {
            const int gbs = (S == 0) ? 3 : (S == 1) ? 552 : (S == 2) ? 1100 : 1648;
            for (int G = tid; G < YGRAN; G += 256) {
                const int w0 = G * 4;
                unsigned int pk[2];
#pragma unroll
                for (int h = 0; h < 2; ++h) {
                    int i0 = t0g + w0 + 2 * h - 32 + S;
                    int i1 = i0 + 1;
                    float a = (i0 >= 0 && i0 < NT) ? yg[i0] : 0.f;
                    float b = (i1 >= 0 && i1 < NT) ? yg[i1] : 0.f;
                    pk[h] = (unsigned int)f2bf(a) | ((unsigned int)f2bf(b) << 16);
                }
                *(uint2*)(lds + YBASE + (size_t)(gbs + G) * 8) = make_uint2(pk[0], pk[1]);
            }
        }
        __syncthreads();

        // ---- MFMA K-loop: this wave's K-steps (chunk3 has 65 steps, wave3 takes 17) ----
        const int nks = (chunk < 3) ? 16 : ((wv == 3) ? 17 : 16);
        int Ga    = 4 * (16 * wv) + g + 2 * r;                       // x granule, tile 0
        int ybyte = YBASE + gb * 8 + (32 * (16 * wv) + 8 * g - r - s + 32) * 2;
        for (int i = 0; i < nks; ++i) {
            bfx8 a0 = *(const bfx8*)(lds + (swz(Ga) << 4));
            bfx8 a1 = *(const bfx8*)(lds + (swz(Ga + 32) << 4));
            bfx4 b0 = *(const bfx4*)(lds + ybyte);
            bfx4 b1 = *(const bfx4*)(lds + ybyte + 8);
            bfx8 bb = {b0[0], b0[1], b0[2], b0[3], b1[0], b1[1], b1[2], b1[3]};
            acc0 = __builtin_amdgcn_mfma_f32_16x16x32_bf16(a0, bb, acc0, 0, 0, 0);
            acc1 = __builtin_amdgcn_mfma_f32_16x16x32_bf16(a1, bb, acc1, 0, 0, 0);
            Ga += 4; ybyte += 64;
        }

        // ---- fused tail lags 512..514: out[512+d] = sum_t x[t+255+d] y[t] ----
#pragma unroll
        for (int b = 0; b < 8; ++b) {
            const int tl = 512 * wv + 64 * b + lane;
            const float yv = bf2f(*(const unsigned short*)(lds + YBASE + 3 * 8 + (size_t)(tl + 32) * 2));
            const int e = tl + 512;
#pragma unroll
            for (int d = 0; d < 3; ++d) {
                const int ee = e + d;
                const float xv = bf2f(*(const unsigned short*)(lds + (swz(ee >> 3) << 4) + (ee & 7) * 2));
                if (d == 0) ta0 = fmaf(xv, yv, ta0);
                else if (d == 1) ta1 = fmaf(xv, yv, ta1);
                else ta2 = fmaf(xv, yv, ta2);
            }
        }
        __syncthreads();
    }

    // ---- epilogue: cross-wave reduce. lag = 256*mt + 64*g + 16*i + r ----
    float* red = (float*)lds;   // 4 waves x 512 floats = 8KB (post-barrier reuse)
#pragma unroll
    for (int i = 0; i < 4; ++i) {
        red[wv * 512 +   0 + 64 * g + 16 * i + r] = acc0[i];
        red[wv * 512 + 256 + 64 * g + 16 * i + r] = acc1[i];
    }
#pragma unroll
    for (int m = 32; m >= 1; m >>= 1) {
        ta0 += __shfl_xor(ta0, m);
        ta1 += __shfl_xor(ta1, m);
        ta2 += __shfl_xor(ta2, m);
    }
    float* redT = (float*)(lds + XBYTES + YBYTES);
    if (lane == 0) { redT[wv * 3 + 0] = ta0; redT[wv * 3 + 1] = ta1; redT[wv * 3 + 2] = ta2; }
    __syncthreads();

    for (int l = tid; l < 512; l += 256)
        og[l] = red[l] + red[512 + l] + red[1024 + l] + red[1536 + l];
    if (tid < 3)
        og[512 + tid] = redT[tid] + redT[3 + tid] + redT[6 + tid] + redT[9 + tid];
}

extern "C" void kernel_launch(void* const* d_in, const int* in_sizes, int n_in,
                              void* d_out, int out_size, void* d_ws, size_t ws_size,
                              hipStream_t stream) {
    const float* d1 = (const float*)d_in[0];   // data1 (x)
    const float* d2 = (const float*)d_in[1];   // data2 (y)
    float* out = (float*)d_out;
    const int nch = in_sizes[0] / NT;          // 32*64 = 2048 channels

    xcorr_mfma<<<dim3(nch), dim3(256), 0, stream>>>(d1, d2, out);
}

// Round 7
// 204.705 us; speedup vs baseline: 2.9471x; 1.4108x over previous
//
#include <hip/hip_runtime.h>

typedef __attribute__((ext_vector_type(4))) float  f32x4;
typedef __attribute__((ext_vector_type(8))) short  bfx8;
typedef __attribute__((ext_vector_type(4))) short  bfx4;

#define NT    8192
#define NF4   2048                // NT/4 float4 slots per channel
#define NOUT  515
#define TCH   2048
#define XGRAN 328                 // x region: 16B granules (8 bf16) -> 2624 elems, 656 f4-slots
#define XBYTES (XGRAN * 16)       // 5248
#define YTASK 536                 // y slot-groups of 4 (granules) per replica
#define YBASE XBYTES
#define YBYTES (2184 * 8)         // replica granule bases {3,552,1100,1648}, end 2184
#define LDSZ  (XBYTES + YBYTES + 64)

// x granule swizzle: XOR low-3 granule bits with block id (bijective in 8-blocks)
__device__ __forceinline__ int swz(int G) { return G ^ ((G >> 3) & 7); }

// packed fp32->bf16 (RNE), 2 elems/instr
__device__ __forceinline__ unsigned cvtpk(float lo, float hi) {
    unsigned r;
    asm("v_cvt_pk_bf16_f32 %0, %1, %2" : "=v"(r) : "v"(lo), "v"(hi));
    return r;
}

__global__ __launch_bounds__(256) void xcorr_mfma(const float* __restrict__ x,
                                                  const float* __restrict__ y,
                                                  float* __restrict__ out) {
    __shared__ __align__(16) char lds[LDSZ];

    const int c    = blockIdx.x;
    const int tid  = threadIdx.x;
    const int lane = tid & 63;
    const int wv   = tid >> 6;
    const int g    = lane >> 4;       // k-group
    const int r    = lane & 15;       // A row (m low) == B col (q)
    const int rc   = (r < 2) ? r : 2; // clamped row for tail tile (rows 3..15 garbage)
    const int s    = (4 - (r & 3)) & 3;                 // y replica id for this col
    const int gb   = (s == 0) ? 3 : (s == 1) ? 552 : (s == 2) ? 1100 : 1648;

    const float4* xg4 = (const float4*)(x + (size_t)c * NT);
    const float4* yg4 = (const float4*)(y + (size_t)c * NT);
    float* og = out + (size_t)c * NOUT;

    f32x4 acc0 = {0.f, 0.f, 0.f, 0.f};   // lags   0..255
    f32x4 acc1 = {0.f, 0.f, 0.f, 0.f};   // lags 256..511
    f32x4 acc2 = {0.f, 0.f, 0.f, 0.f};   // lags 512..514 (row 0, cols 0..2; rest garbage)

    const float4 z4 = make_float4(0.f, 0.f, 0.f, 0.f);

    for (int chunk = 0; chunk < 4; ++chunk) {
        const int t04 = chunk * (TCH / 4);     // chunk base in f4 slots

        // ---- stage x: LDS elem e <-> xg[t0 + e - 257]; slot j covers elems 4j..4j+3
        //      = global f4 (t04+j-65).w , (t04+j-64).xyz  — coalesced, f4-exact guards
        for (int j = tid; j < 656; j += 256) {
            const int s0 = t04 + j - 65;
            const float4 A = ((unsigned)s0 < (unsigned)NF4)       ? xg4[s0]     : z4;
            const float4 B = ((unsigned)(s0 + 1) < (unsigned)NF4) ? xg4[s0 + 1] : z4;
            *(uint2*)(lds + (swz(j >> 1) << 4) + ((j & 1) << 3)) =
                make_uint2(cvtpk(A.w, B.x), cvtpk(B.y, B.z));
        }

        // ---- stage y replicas (all 4 from one load pair): replica S slot w <->
        //      yg[t0 + w - 32 + S]; task j covers slots 4j..4j+3 of every replica
        for (int j = tid; j < YTASK; j += 256) {
            const int s0 = t04 + j - 8;
            const float4 A = ((unsigned)s0 < (unsigned)NF4)       ? yg4[s0]     : z4;
            const float4 B = ((unsigned)(s0 + 1) < (unsigned)NF4) ? yg4[s0 + 1] : z4;
            char* yb = lds + YBASE + (size_t)j * 8;
            *(uint2*)(yb + 3    * 8) = make_uint2(cvtpk(A.x, A.y), cvtpk(A.z, A.w));
            *(uint2*)(yb + 552  * 8) = make_uint2(cvtpk(A.y, A.z), cvtpk(A.w, B.x));
            *(uint2*)(yb + 1100 * 8) = make_uint2(cvtpk(A.z, A.w), cvtpk(B.x, B.y));
            *(uint2*)(yb + 1648 * 8) = make_uint2(cvtpk(A.w, B.x), cvtpk(B.y, B.z));
        }
        __syncthreads();

        // ---- MFMA K-loop (wave wv owns k-local [512wv, 512wv+512); chunk3 wave3: +32)
        const int nks = (chunk < 3) ? 16 : ((wv == 3) ? 17 : 16);
        int Ga    = 64 * wv + g + 2 * r;            // x granule, lag-tile 0
        int Ga2   = 64 * wv + g + 2 * rc + 64;      // x granule, tail tile (clamped row)
        int ybyte = YBASE + gb * 8 + (32 * (16 * wv) + 8 * g - r - s + 32) * 2;
        for (int i = 0; i < nks; ++i) {
            bfx8 a0 = *(const bfx8*)(lds + (swz(Ga) << 4));
            bfx8 a1 = *(const bfx8*)(lds + (swz(Ga + 32) << 4));
            bfx8 a2 = *(const bfx8*)(lds + (swz(Ga2) << 4));
            bfx4 b0 = *(const bfx4*)(lds + ybyte);
            bfx4 b1 = *(const bfx4*)(lds + ybyte + 8);
            bfx8 bb = {b0[0], b0[1], b0[2], b0[3], b1[0], b1[1], b1[2], b1[3]};
            acc0 = __builtin_amdgcn_mfma_f32_16x16x32_bf16(a0, bb, acc0, 0, 0, 0);
            acc1 = __builtin_amdgcn_mfma_f32_16x16x32_bf16(a1, bb, acc1, 0, 0, 0);
            acc2 = __builtin_amdgcn_mfma_f32_16x16x32_bf16(a2, bb, acc2, 0, 0, 0);
            Ga += 4; Ga2 += 4; ybyte += 64;
        }
        __syncthreads();
    }

    // ---- epilogue: per-wave partials in LDS, then cross-wave sum. lag = 256*mt+64g+16i+r
    float* red = (float*)lds;          // 4 waves x 768 floats = 12 KB
#pragma unroll
    for (int i = 0; i < 4; ++i) {
        red[wv * 768 +   0 + 64 * g + 16 * i + r] = acc0[i];
        red[wv * 768 + 256 + 64 * g + 16 * i + r] = acc1[i];
    }
    if (g == 0 && r < 3) red[wv * 768 + 512 + r] = acc2[0];   // lag 512+r (row 0, col r)
    __syncthreads();

    for (int l = tid; l < NOUT; l += 256)
        og[l] = red[l] + red[768 + l] + red[1536 + l] + red[2304 + l];
}

extern "C" void kernel_launch(void* const* d_in, const int* in_sizes, int n_in,
                              void* d_out, int out_size, void* d_ws, size_t ws_size,
                              hipStream_t stream) {
    const float* d1 = (const float*)d_in[0];   // data1 (x)
    const float* d2 = (const float*)d_in[1];   // data2 (y)
    float* out = (float*)d_out;
    const int nch = in_sizes[0] / NT;          // 32*64 = 2048 channels

    xcorr_mfma<<<dim3(nch), dim3(256), 0, stream>>>(d1, d2, out);
}

// Round 9
// 191.751 us; speedup vs baseline: 3.1462x; 1.0676x over previous
//
#include <hip/hip_runtime.h>

typedef __attribute__((ext_vector_type(4))) float  f32x4;
typedef __attribute__((ext_vector_type(8))) short  bfx8;
typedef __attribute__((ext_vector_type(4))) short  bfx4;

#define NT     8192
#define NF4    2048               // float4 slots per channel
#define NOUT   515
#define NCHUNK 8
#define T04    256                // f4 slots per chunk (1024 elems)
#define XSLOT  400                // x region: 400 uint2-slots = 200 granules = 1600 elems
#define XBYTES 3200
#define YTASK  273                // y granule-tasks per replica (1092 slots)
#define YBASE  XBYTES
// y replica granule bases (mod 16 = {3,8,12,0} for bank spread), end 1105 gran = 8840 B
#define LDSZ   24576              // epilogue: 8 waves x 768 floats

__device__ __forceinline__ int swz(int G) { return G ^ ((G >> 3) & 7); }

__device__ __forceinline__ unsigned cvtpk(float lo, float hi) {
    unsigned r;
    asm("v_cvt_pk_bf16_f32 %0, %1, %2" : "=v"(r) : "v"(lo), "v"(hi));
    return r;
}

__global__ __launch_bounds__(512, 8) void xcorr_mfma(const float* __restrict__ x,
                                                     const float* __restrict__ y,
                                                     float* __restrict__ out) {
    __shared__ __align__(16) char lds[LDSZ];

    const int c    = blockIdx.x;
    const int tid  = threadIdx.x;
    const int lane = tid & 63;
    const int wv   = tid >> 6;        // 8 waves
    const int g    = lane >> 4;       // k-group
    const int r    = lane & 15;       // A row == B col (q)
    const int rc   = (r < 2) ? r : 2; // clamped row for tail tile
    const int s    = (4 - (r & 3)) & 3;
    const int gb   = (s == 0) ? 3 : (s == 1) ? 280 : (s == 2) ? 556 : 832;

    const float4* xg4 = (const float4*)(x + (size_t)c * NT);
    const float4* yg4 = (const float4*)(y + (size_t)c * NT);
    float* og = out + (size_t)c * NOUT;

    f32x4 acc0 = {0.f,0.f,0.f,0.f};   // lags   0..255
    f32x4 acc1 = {0.f,0.f,0.f,0.f};   // lags 256..511
    f32x4 acc2 = {0.f,0.f,0.f,0.f};   // lags 512..514 (row0 cols0..2; rest garbage)

    const float4 z4 = make_float4(0.f,0.f,0.f,0.f);
    float4 pxA, pxB, pyA, pyB;        // prefetched staging registers

    // ---- prefetch chunk 0 (clamped, branchless; zeroing happens at write) ----
    {
        const int sx = tid - 65;
        pxA = xg4[min(max(sx, 0),     NF4 - 1)];
        pxB = xg4[min(max(sx + 1, 0), NF4 - 1)];
        const int sy = tid - 8;
        pyA = yg4[min(max(sy, 0),     NF4 - 1)];
        pyB = yg4[min(max(sy + 1, 0), NF4 - 1)];
    }

    for (int ch = 0; ch < NCHUNK; ++ch) {
        // ---- stage from prefetched regs (edge-zeroing only chunks 0/7) ----
        const bool edge = (ch == 0) | (ch == NCHUNK - 1);
        if (tid < XSLOT) {
            const int s0 = T04 * ch + tid - 65;
            float4 A = pxA, B = pxB;
            if (edge) {
                if ((unsigned)s0       >= (unsigned)NF4) A = z4;
                if ((unsigned)(s0 + 1) >= (unsigned)NF4) B = z4;
            }
            *(uint2*)(lds + (swz(tid >> 1) << 4) + ((tid & 1) << 3)) =
                make_uint2(cvtpk(A.w, B.x), cvtpk(B.y, B.z));
        }
        if (tid < YTASK) {
            const int s0 = T04 * ch + tid - 8;
            float4 A = pyA, B = pyB;
            if (edge) {
                if ((unsigned)s0       >= (unsigned)NF4) A = z4;
                if ((unsigned)(s0 + 1) >= (unsigned)NF4) B = z4;
            }
            char* yb = lds + YBASE + (size_t)tid * 8;
            *(uint2*)(yb + 3   * 8) = make_uint2(cvtpk(A.x, A.y), cvtpk(A.z, A.w));
            *(uint2*)(yb + 280 * 8) = make_uint2(cvtpk(A.y, A.z), cvtpk(A.w, B.x));
            *(uint2*)(yb + 556 * 8) = make_uint2(cvtpk(A.z, A.w), cvtpk(B.x, B.y));
            *(uint2*)(yb + 832 * 8) = make_uint2(cvtpk(A.w, B.x), cvtpk(B.y, B.z));
        }
        // ---- issue next chunk's loads NOW (fly during compute) ----
        if (ch + 1 < NCHUNK) {
            const int sx = T04 * (ch + 1) + tid - 65;
            pxA = xg4[min(max(sx, 0),     NF4 - 1)];
            pxB = xg4[min(max(sx + 1, 0), NF4 - 1)];
            const int sy = T04 * (ch + 1) + tid - 8;
            pyA = yg4[min(max(sy, 0),     NF4 - 1)];
            pyB = yg4[min(max(sy + 1, 0), NF4 - 1)];
        }
        __syncthreads();

        // ---- MFMA K-loop: wave wv owns k-local [128wv, 128wv+128); last wave +1 step
        const int nks = (ch == NCHUNK - 1 && wv == 7) ? 5 : 4;
        int Ga    = 16 * wv + g + 2 * r;
        int Ga2   = 16 * wv + g + 2 * rc + 64;
        int ybyte = YBASE + gb * 8 + (128 * wv + 8 * g - r - s + 32) * 2;
        for (int i = 0; i < nks; ++i) {
            bfx8 a0 = *(const bfx8*)(lds + (swz(Ga) << 4));
            bfx8 a1 = *(const bfx8*)(lds + (swz(Ga + 32) << 4));
            bfx8 a2 = *(const bfx8*)(lds + (swz(Ga2) << 4));
            bfx4 b0 = *(const bfx4*)(lds + ybyte);
            bfx4 b1 = *(const bfx4*)(lds + ybyte + 8);
            bfx8 bb = {b0[0],b0[1],b0[2],b0[3], b1[0],b1[1],b1[2],b1[3]};
            acc0 = __builtin_amdgcn_mfma_f32_16x16x32_bf16(a0, bb, acc0, 0, 0, 0);
            acc1 = __builtin_amdgcn_mfma_f32_16x16x32_bf16(a1, bb, acc1, 0, 0, 0);
            acc2 = __builtin_amdgcn_mfma_f32_16x16x32_bf16(a2, bb, acc2, 0, 0, 0);
            Ga += 4; Ga2 += 4; ybyte += 64;
        }
        __syncthreads();
    }

    // ---- epilogue: per-wave partials, cross-wave sum. lag = 256*mt + 64g + 16i + r
    float* red = (float*)lds;      // 8 waves x 768 floats
#pragma unroll
    for (int i = 0; i < 4; ++i) {
        red[wv * 768 +   0 + 64 * g + 16 * i + r] = acc0[i];
        red[wv * 768 + 256 + 64 * g + 16 * i + r] = acc1[i];
    }
    if (g == 0 && r < 3) red[wv * 768 + 512 + r] = acc2[0];
    __syncthreads();

    for (int l = tid; l < NOUT; l += 512) {
        float v = 0.f;
#pragma unroll
        for (int w = 0; w < 8; ++w) v += red[w * 768 + l];
        og[l] = v;
    }
}

extern "C" void kernel_launch(void* const* d_in, const int* in_sizes, int n_in,
                              void* d_out, int out_size, void* d_ws, size_t ws_size,
                              hipStream_t stream) {
    const float* d1 = (const float*)d_in[0];   // data1 (x)
    const float* d2 = (const float*)d_in[1];   // data2 (y)
    float* out = (float*)d_out;
    const int nch = in_sizes[0] / NT;          // 32*64 = 2048 channels

    xcorr_mfma<<<dim3(nch), dim3(512), 0, stream>>>(d1, d2, out);
}